// Round 3
// baseline (323.397 us; speedup 1.0000x reference)
//
#include <hip/hip_runtime.h>
#include <math.h>

#define BATCH 4
#define TU 4096
#define TM 2048
#define DM 1024
#define FF 2048          // 2*D
#define KB 4             // max births
#define NROWS (BATCH*KB) // 16
#define OUT_TM (TM+KB)   // 2052

typedef float fv4 __attribute__((ext_vector_type(4)));

// ---- kernel 1: row means of r_emer + copy o_macro->out + u = W^T w_gate ----
// grid = 4096 (mean+copy) + 8 (u) blocks
__global__ __launch_bounds__(256) void k_mean_copy_u(
    const float* __restrict__ r_emer, const float* __restrict__ o_macro,
    const float* __restrict__ W, const float* __restrict__ w_gate,
    float* __restrict__ micro_res, float* __restrict__ u,
    float* __restrict__ out)
{
    const int tid  = threadIdx.x;
    const int lane = tid & 63;
    const int wave = tid >> 6;

    if (blockIdx.x < 4096) {
        // Part A: one wave per row, mean over 2048 floats (nt fv4 loads)
        const int row = blockIdx.x * 4 + wave;           // 0..16383
        const fv4* rp = (const fv4*)(r_emer + (size_t)row * FF);
        fv4 a[8];
        #pragma unroll
        for (int j = 0; j < 8; ++j)
            a[j] = __builtin_nontemporal_load(rp + lane + 64 * j);

        // Part B: streaming copy o_macro -> out (batch-strided dst)
        const fv4* src = (const fv4*)o_macro;
        fv4* dst = (fv4*)out;
        const int e0 = blockIdx.x * 256 + tid;
        #pragma unroll
        for (int it = 0; it < 2; ++it) {
            int e = e0 + it * (4096 * 256);              // < 2097152
            int b = e >> 19;
            int q = e & ((1 << 19) - 1);
            fv4 v = __builtin_nontemporal_load(src + e);
            __builtin_nontemporal_store(v, dst + (size_t)b * (OUT_TM * DM / 4) + q);
        }

        // finish Part A
        float s = 0.0f;
        #pragma unroll
        for (int j = 0; j < 8; ++j) s += a[j].x + a[j].y + a[j].z + a[j].w;
        #pragma unroll
        for (int off = 32; off >= 1; off >>= 1)
            s += __shfl_down(s, off, 64);
        if (lane == 0) micro_res[row] = s * (1.0f / 2048.0f);
    } else {
        // u[f] = sum_d w_gate[d] * W[d][f];  8 blocks x 256 f each
        const int bid = blockIdx.x - 4096;               // 0..7
        const float4* W4 = (const float4*)W;
        const int col = bid * 64 + lane;                 // float4 col in [0,512)
        float4 acc = make_float4(0.f, 0.f, 0.f, 0.f);
        const int d0 = wave * 256;
        for (int d = d0; d < d0 + 256; ++d) {
            float g = w_gate[d];
            float4 wv = W4[(size_t)d * 512 + col];
            acc.x += g * wv.x; acc.y += g * wv.y;
            acc.z += g * wv.z; acc.w += g * wv.w;
        }
        __shared__ float4 part[4][64];
        part[wave][lane] = acc;
        __syncthreads();
        if (tid < 64) {
            float4 s0 = part[0][tid], s1 = part[1][tid];
            float4 s2 = part[2][tid], s3 = part[3][tid];
            float4 r;
            r.x = s0.x + s1.x + s2.x + s3.x;
            r.y = s0.y + s1.y + s2.y + s3.y;
            r.z = s0.z + s1.z + s2.z + s3.z;
            r.w = s0.w + s1.w + s2.w + s3.w;
            ((float4*)u)[bid * 64 + tid] = r;
        }
    }
}

// ---- kernel 2: per-batch top-4 + gate scales (4 blocks) --------------------
__global__ __launch_bounds__(256) void k_topk_gate(
    const float* __restrict__ micro_res, const float* __restrict__ threshold_bias,
    const float* __restrict__ u, const float* __restrict__ o_micro,
    const float* __restrict__ b_gate,
    int* __restrict__ topk_idx, float* __restrict__ scale,
    float* __restrict__ counts)
{
    __shared__ float res[TU];     // 16 KB
    __shared__ float rv[256];
    __shared__ int   ri[256];
    __shared__ int   sel[KB];
    __shared__ float selv[KB];
    __shared__ float red[4];
    __shared__ float sc[KB];

    const int b = blockIdx.x, tid = threadIdx.x;
    const int lane = tid & 63, wave = tid >> 6;
    const float* mr = micro_res + b * TU;
    for (int i = tid; i < TU; i += 256) res[i] = mr[i];
    __syncthreads();

    const float thr = 0.45f + tanhf(threshold_bias[0]) * 0.2f;

    for (int p = 0; p < KB; ++p) {
        float bv = -1.0f; int bi = 0x7fffffff;
        for (int t = tid; t < TU - 1; t += 256) {
            bool skip = false;
            for (int q = 0; q < p; ++q) if (sel[q] == t) skip = true;
            if (skip) continue;
            float pr = (res[t] + res[t + 1]) * 0.5f;
            float scv = pr > thr ? pr : 0.0f;
            if (scv > bv || (scv == bv && t < bi)) { bv = scv; bi = t; }
        }
        rv[tid] = bv; ri[tid] = bi;
        __syncthreads();
        for (int s = 128; s >= 1; s >>= 1) {
            if (tid < s) {
                float ov = rv[tid + s]; int oi = ri[tid + s];
                if (ov > rv[tid] || (ov == rv[tid] && oi < ri[tid])) {
                    rv[tid] = ov; ri[tid] = oi;
                }
            }
            __syncthreads();
        }
        if (tid == 0) { sel[p] = ri[0]; selv[p] = rv[0]; }
        __syncthreads();
    }

    // gate for this batch's 4 candidate rows: sigmoid(u . combined + b_gate)
    const int f0 = tid * 8;
    const float4* up = (const float4*)(u + f0);
    const float4 u0 = up[0], u1 = up[1];
    for (int k = 0; k < KB; ++k) {
        const int idx = sel[k];
        const float* srcrow;
        int fo;
        if (f0 < DM) { srcrow = o_micro + ((size_t)b * TU + idx) * DM;     fo = f0; }
        else         { srcrow = o_micro + ((size_t)b * TU + idx + 1) * DM; fo = f0 - DM; }
        const float4* cp = (const float4*)(srcrow + fo);
        float4 c0 = cp[0], c1 = cp[1];
        float dsum = c0.x * u0.x + c0.y * u0.y + c0.z * u0.z + c0.w * u0.w
                   + c1.x * u1.x + c1.y * u1.y + c1.z * u1.z + c1.w * u1.w;
        #pragma unroll
        for (int off = 32; off >= 1; off >>= 1)
            dsum += __shfl_down(dsum, off, 64);
        if (lane == 0) red[wave] = dsum;
        __syncthreads();
        if (tid == 0) {
            float tot = red[0] + red[1] + red[2] + red[3] + b_gate[0];
            float g = 1.0f / (1.0f + expf(-tot));
            float m = selv[k] > 0.0f ? 1.0f : 0.0f;
            sc[k] = g * m;
        }
        __syncthreads();
    }

    if (tid < KB) {
        topk_idx[b * KB + tid] = sel[tid];
        scale[b * KB + tid] = sc[tid];
    }
    if (tid == 0) {
        float c = 0.f;
        for (int k = 0; k < KB; ++k) c += (selv[k] > 0.0f) ? 1.0f : 0.0f;
        counts[b] = c;
    }
}

// ---- kernel 3: children -> out directly (1024 blocks, one per d) -----------
__global__ __launch_bounds__(256) void k_child_out(
    const float* __restrict__ o_micro, const float* __restrict__ W,
    const int* __restrict__ topk_idx, const float* __restrict__ scale,
    const float* __restrict__ counts, float* __restrict__ out)
{
    const int d   = blockIdx.x;       // 0..1023
    const int tid = threadIdx.x;
    const int lane = tid & 63;
    const int wave = tid >> 6;
    const int f0  = tid * 8;

    __shared__ int   sidx[NROWS];
    __shared__ float ssc[NROWS];
    if (tid < NROWS) { sidx[tid] = topk_idx[tid]; ssc[tid] = scale[tid]; }
    __syncthreads();

    const float4* wp = (const float4*)(W + (size_t)d * FF + f0);
    const float4 w0 = wp[0], w1 = wp[1];

    float acc[NROWS];
    #pragma unroll
    for (int r = 0; r < NROWS; ++r) {
        const int bb  = r >> 2;
        const int idx = sidx[r];
        const float* srcrow;
        int fo;
        if (f0 < DM) { srcrow = o_micro + ((size_t)bb * TU + idx) * DM;     fo = f0; }
        else         { srcrow = o_micro + ((size_t)bb * TU + idx + 1) * DM; fo = f0 - DM; }
        const float4* cp = (const float4*)(srcrow + fo);
        float4 c0 = cp[0], c1 = cp[1];
        acc[r] = c0.x * w0.x + c0.y * w0.y + c0.z * w0.z + c0.w * w0.w
               + c1.x * w1.x + c1.y * w1.y + c1.z * w1.z + c1.w * w1.w;
    }

    #pragma unroll
    for (int r = 0; r < NROWS; ++r) {
        float v = acc[r];
        #pragma unroll
        for (int off = 32; off >= 1; off >>= 1)
            v += __shfl_down(v, off, 64);
        acc[r] = v;
    }
    __shared__ float part[4][NROWS];
    if (lane == 0) {
        #pragma unroll
        for (int r = 0; r < NROWS; ++r) part[wave][r] = acc[r];
    }
    __syncthreads();
    if (tid < NROWS) {
        float v = (part[0][tid] + part[1][tid] + part[2][tid] + part[3][tid]) * ssc[tid];
        out[((size_t)(tid >> 2) * OUT_TM + TM + (tid & 3)) * DM + d] = v;
    }
    if (blockIdx.x == 0 && tid == 0)
        out[(size_t)BATCH * OUT_TM * DM] =
            counts[0] + counts[1] + counts[2] + counts[3];   // n_births
}

extern "C" void kernel_launch(void* const* d_in, const int* in_sizes, int n_in,
                              void* d_out, int out_size, void* d_ws, size_t ws_size,
                              hipStream_t stream) {
    const float* o_micro   = (const float*)d_in[0];
    const float* o_macro   = (const float*)d_in[1];
    const float* r_emer    = (const float*)d_in[2];
    // d_in[3] chunk_size — unused by the reference
    const float* W_vesica  = (const float*)d_in[4];
    const float* w_gate    = (const float*)d_in[5];
    const float* b_gate    = (const float*)d_in[6];
    const float* thr_bias  = (const float*)d_in[7];
    float* out = (float*)d_out;

    // workspace layout (floats)
    float* wsf       = (float*)d_ws;
    float* micro_res = wsf;                    // 16384 floats
    float* u         = wsf + 16384;            // 2048 floats
    int*   topk_idx  = (int*)(wsf + 18432);    // 16 ints
    float* scale     = wsf + 18448;            // 16 floats
    float* counts    = wsf + 18464;            // 4 floats

    k_mean_copy_u<<<4104, 256, 0, stream>>>(r_emer, o_macro, W_vesica, w_gate,
                                            micro_res, u, out);
    k_topk_gate<<<BATCH, 256, 0, stream>>>(micro_res, thr_bias, u, o_micro,
                                           b_gate, topk_idx, scale, counts);
    k_child_out<<<DM, 256, 0, stream>>>(o_micro, W_vesica, topk_idx, scale,
                                        counts, out);
}

// Round 4
// 315.601 us; speedup vs baseline: 1.0247x; 1.0247x over previous
//
#include <hip/hip_runtime.h>
#include <math.h>

#define BATCH 4
#define TU 4096
#define TM 2048
#define DM 1024
#define FF 2048          // 2*D
#define KB 4             // max births
#define NROWS (BATCH*KB) // 16
#define OUT_TM (TM+KB)   // 2052

typedef float fv4 __attribute__((ext_vector_type(4)));
typedef unsigned long long u64;

// ---- kernel 1: row means of r_emer + copy o_macro->out + u = W^T w_gate ----
// grid = 4096 (mean+copy) + 8 (u) blocks
__global__ __launch_bounds__(256) void k_mean_copy_u(
    const float* __restrict__ r_emer, const float* __restrict__ o_macro,
    const float* __restrict__ W, const float* __restrict__ w_gate,
    float* __restrict__ micro_res, float* __restrict__ u,
    float* __restrict__ out)
{
    const int tid  = threadIdx.x;
    const int lane = tid & 63;
    const int wave = tid >> 6;

    if (blockIdx.x < 4096) {
        // Part A: one wave per row, mean over 2048 floats (nt fv4 loads)
        const int row = blockIdx.x * 4 + wave;           // 0..16383
        const fv4* rp = (const fv4*)(r_emer + (size_t)row * FF);
        fv4 a[8];
        #pragma unroll
        for (int j = 0; j < 8; ++j)
            a[j] = __builtin_nontemporal_load(rp + lane + 64 * j);

        // Part B: streaming copy o_macro -> out (batch-strided dst)
        const fv4* src = (const fv4*)o_macro;
        fv4* dst = (fv4*)out;
        const int e0 = blockIdx.x * 256 + tid;
        #pragma unroll
        for (int it = 0; it < 2; ++it) {
            int e = e0 + it * (4096 * 256);              // < 2097152
            int b = e >> 19;
            int q = e & ((1 << 19) - 1);
            fv4 v = __builtin_nontemporal_load(src + e);
            __builtin_nontemporal_store(v, dst + (size_t)b * (OUT_TM * DM / 4) + q);
        }

        // finish Part A
        float s = 0.0f;
        #pragma unroll
        for (int j = 0; j < 8; ++j) s += a[j].x + a[j].y + a[j].z + a[j].w;
        #pragma unroll
        for (int off = 32; off >= 1; off >>= 1)
            s += __shfl_down(s, off, 64);
        if (lane == 0) micro_res[row] = s * (1.0f / 2048.0f);
    } else {
        // u[f] = sum_d w_gate[d] * W[d][f];  8 blocks x 256 f each
        const int bid = blockIdx.x - 4096;               // 0..7
        const float4* W4 = (const float4*)W;
        const int col = bid * 64 + lane;                 // float4 col in [0,512)
        float4 acc = make_float4(0.f, 0.f, 0.f, 0.f);
        const int d0 = wave * 256;
        for (int d = d0; d < d0 + 256; ++d) {
            float g = w_gate[d];
            float4 wv = W4[(size_t)d * 512 + col];
            acc.x += g * wv.x; acc.y += g * wv.y;
            acc.z += g * wv.z; acc.w += g * wv.w;
        }
        __shared__ float4 part[4][64];
        part[wave][lane] = acc;
        __syncthreads();
        if (tid < 64) {
            float4 s0 = part[0][tid], s1 = part[1][tid];
            float4 s2 = part[2][tid], s3 = part[3][tid];
            float4 r;
            r.x = s0.x + s1.x + s2.x + s3.x;
            r.y = s0.y + s1.y + s2.y + s3.y;
            r.z = s0.z + s1.z + s2.z + s3.z;
            r.w = s0.w + s1.w + s2.w + s3.w;
            ((float4*)u)[bid * 64 + tid] = r;
        }
    }
}

// ---- kernel 2: per-batch single-pass top-4 + gate scales (4 blocks) --------
// packed key: (score_bits << 32) | (0xFFFFFFFF - idx)
//   scores are >= 0 so uint bits preserve float order; inverted idx makes
//   equal-score comparisons pick the LOWER index (lax.top_k tie semantics).
__global__ __launch_bounds__(1024) void k_topk_gate(
    const float* __restrict__ micro_res, const float* __restrict__ threshold_bias,
    const float* __restrict__ u, const float* __restrict__ o_micro,
    const float* __restrict__ b_gate,
    int* __restrict__ topk_idx, float* __restrict__ scale,
    float* __restrict__ counts)
{
    __shared__ float res[TU];          // 16 KB
    __shared__ u64   lst[1024][4];     // 32 KB
    __shared__ int   sel[KB];
    __shared__ float selv[KB];
    __shared__ float red[16];
    __shared__ float sc[KB];

    const int b = blockIdx.x, tid = threadIdx.x;
    const int lane = tid & 63, wave = tid >> 6;

    ((float4*)res)[tid] = ((const float4*)(micro_res + b * TU))[tid];
    __syncthreads();

    const float thr = 0.45f + tanhf(threshold_bias[0]) * 0.2f;

    // per-thread sorted (desc) top-4 of its 4 candidates
    u64 l[4] = {0ull, 0ull, 0ull, 0ull};
    #pragma unroll
    for (int j = 0; j < 4; ++j) {
        int t = tid + j * 1024;
        if (t >= TU - 1) continue;
        float pr = (res[t] + res[t + 1]) * 0.5f;
        float s  = pr > thr ? pr : 0.0f;
        u64 key = ((u64)__float_as_uint(s) << 32) | (u64)(0xFFFFFFFFu - (unsigned)t);
        if (key > l[3]) {
            l[3] = key;
            #pragma unroll
            for (int i = 3; i > 0; --i)
                if (l[i] > l[i - 1]) { u64 tmp = l[i]; l[i] = l[i - 1]; l[i - 1] = tmp; }
        }
    }
    lst[tid][0] = l[0]; lst[tid][1] = l[1]; lst[tid][2] = l[2]; lst[tid][3] = l[3];
    __syncthreads();

    // tree merge of sorted 4-lists
    for (int s = 512; s >= 1; s >>= 1) {
        if (tid < s) {
            u64 a0 = lst[tid][0],   a1 = lst[tid][1],   a2 = lst[tid][2],   a3 = lst[tid][3];
            u64 b0 = lst[tid+s][0], b1 = lst[tid+s][1], b2 = lst[tid+s][2], b3 = lst[tid+s][3];
            u64 a[4] = {a0, a1, a2, a3};
            u64 c[4] = {b0, b1, b2, b3};
            u64 o[4]; int ia = 0, ib = 0;
            #pragma unroll
            for (int i = 0; i < 4; ++i) {
                bool ta = (ib >= 4) || (ia < 4 && a[ia] >= c[ib]);
                o[i] = ta ? a[ia] : c[ib];
                ia += ta ? 1 : 0; ib += ta ? 0 : 1;
            }
            lst[tid][0] = o[0]; lst[tid][1] = o[1]; lst[tid][2] = o[2]; lst[tid][3] = o[3];
        }
        __syncthreads();
    }

    if (tid < KB) {
        u64 key = lst[0][tid];
        sel[tid]  = (int)(0xFFFFFFFFu - (unsigned)(key & 0xFFFFFFFFu));
        selv[tid] = __uint_as_float((unsigned)(key >> 32));
    }
    __syncthreads();

    // gate: sigmoid(u . combined + b_gate) for the 4 candidates
    const float2 uv = ((const float2*)u)[tid];   // f0 = tid*2
    const int f0 = tid * 2;
    for (int k = 0; k < KB; ++k) {
        const int idx = sel[k];
        const float* srcrow;
        int fo;
        if (f0 < DM) { srcrow = o_micro + ((size_t)b * TU + idx) * DM;     fo = f0; }
        else         { srcrow = o_micro + ((size_t)b * TU + idx + 1) * DM; fo = f0 - DM; }
        float2 c = *(const float2*)(srcrow + fo);
        float dsum = c.x * uv.x + c.y * uv.y;
        #pragma unroll
        for (int off = 32; off >= 1; off >>= 1)
            dsum += __shfl_down(dsum, off, 64);
        if (lane == 0) red[wave] = dsum;
        __syncthreads();
        if (tid == 0) {
            float tot = b_gate[0];
            #pragma unroll
            for (int w = 0; w < 16; ++w) tot += red[w];
            float g = 1.0f / (1.0f + expf(-tot));
            float m = selv[k] > 0.0f ? 1.0f : 0.0f;
            sc[k] = g * m;
        }
        __syncthreads();
    }

    if (tid < KB) {
        topk_idx[b * KB + tid] = sel[tid];
        scale[b * KB + tid] = sc[tid];
    }
    if (tid == 0) {
        float c = 0.f;
        for (int k = 0; k < KB; ++k) c += (selv[k] > 0.0f) ? 1.0f : 0.0f;
        counts[b] = c;
    }
}

// ---- kernel 3: children -> out directly (1024 blocks, one per d) -----------
__global__ __launch_bounds__(256) void k_child_out(
    const float* __restrict__ o_micro, const float* __restrict__ W,
    const int* __restrict__ topk_idx, const float* __restrict__ scale,
    const float* __restrict__ counts, float* __restrict__ out)
{
    const int d   = blockIdx.x;       // 0..1023
    const int tid = threadIdx.x;
    const int lane = tid & 63;
    const int wave = tid >> 6;
    const int f0  = tid * 8;

    __shared__ int   sidx[NROWS];
    __shared__ float ssc[NROWS];
    if (tid < NROWS) { sidx[tid] = topk_idx[tid]; ssc[tid] = scale[tid]; }
    __syncthreads();

    const float4* wp = (const float4*)(W + (size_t)d * FF + f0);
    const float4 w0 = wp[0], w1 = wp[1];

    float acc[NROWS];
    #pragma unroll
    for (int r = 0; r < NROWS; ++r) {
        const int bb  = r >> 2;
        const int idx = sidx[r];
        const float* srcrow;
        int fo;
        if (f0 < DM) { srcrow = o_micro + ((size_t)bb * TU + idx) * DM;     fo = f0; }
        else         { srcrow = o_micro + ((size_t)bb * TU + idx + 1) * DM; fo = f0 - DM; }
        const float4* cp = (const float4*)(srcrow + fo);
        float4 c0 = cp[0], c1 = cp[1];
        acc[r] = c0.x * w0.x + c0.y * w0.y + c0.z * w0.z + c0.w * w0.w
               + c1.x * w1.x + c1.y * w1.y + c1.z * w1.z + c1.w * w1.w;
    }

    #pragma unroll
    for (int r = 0; r < NROWS; ++r) {
        float v = acc[r];
        #pragma unroll
        for (int off = 32; off >= 1; off >>= 1)
            v += __shfl_down(v, off, 64);
        acc[r] = v;
    }
    __shared__ float part[4][NROWS];
    if (lane == 0) {
        #pragma unroll
        for (int r = 0; r < NROWS; ++r) part[wave][r] = acc[r];
    }
    __syncthreads();
    if (tid < NROWS) {
        float v = (part[0][tid] + part[1][tid] + part[2][tid] + part[3][tid]) * ssc[tid];
        out[((size_t)(tid >> 2) * OUT_TM + TM + (tid & 3)) * DM + d] = v;
    }
    if (blockIdx.x == 0 && tid == 0)
        out[(size_t)BATCH * OUT_TM * DM] =
            counts[0] + counts[1] + counts[2] + counts[3];   // n_births
}

extern "C" void kernel_launch(void* const* d_in, const int* in_sizes, int n_in,
                              void* d_out, int out_size, void* d_ws, size_t ws_size,
                              hipStream_t stream) {
    const float* o_micro   = (const float*)d_in[0];
    const float* o_macro   = (const float*)d_in[1];
    const float* r_emer    = (const float*)d_in[2];
    // d_in[3] chunk_size — unused by the reference
    const float* W_vesica  = (const float*)d_in[4];
    const float* w_gate    = (const float*)d_in[5];
    const float* b_gate    = (const float*)d_in[6];
    const float* thr_bias  = (const float*)d_in[7];
    float* out = (float*)d_out;

    // workspace layout (floats)
    float* wsf       = (float*)d_ws;
    float* micro_res = wsf;                    // 16384 floats
    float* u         = wsf + 16384;            // 2048 floats
    int*   topk_idx  = (int*)(wsf + 18432);    // 16 ints
    float* scale     = wsf + 18448;            // 16 floats
    float* counts    = wsf + 18464;            // 4 floats

    k_mean_copy_u<<<4104, 256, 0, stream>>>(r_emer, o_macro, W_vesica, w_gate,
                                            micro_res, u, out);
    k_topk_gate<<<BATCH, 1024, 0, stream>>>(micro_res, thr_bias, u, o_micro,
                                            b_gate, topk_idx, scale, counts);
    k_child_out<<<DM, 256, 0, stream>>>(o_micro, W_vesica, topk_idx, scale,
                                        counts, out);
}